// Round 10
// baseline (244.083 us; speedup 1.0000x reference)
//
#include <hip/hip_runtime.h>

#define N_NODES 50000
#define NIN 512
#define NH 96
#define NL 32
#define NH2 64

#define SCAN_BLK 49

typedef __attribute__((ext_vector_type(8))) short short8v;   // 8 bf16 (4 VGPR)
typedef __attribute__((ext_vector_type(4))) float f32x4;

__device__ __forceinline__ unsigned short f2bf(float f) {    // RNE f32->bf16
    unsigned u = __float_as_uint(f);
    u = (u + 0x7FFFu + ((u >> 16) & 1u)) >> 16;
    return (unsigned short)u;
}
__device__ __forceinline__ float bf2f(unsigned short h) {
    return __uint_as_float((unsigned)h << 16);
}

__global__ void k_zero_int(int* __restrict__ p, int n) {
    int i = blockIdx.x * blockDim.x + threadIdx.x;
    if (i < n) p[i] = 0;
}

__global__ void k_degi(const int* __restrict__ dst, int* __restrict__ degi, int E) {
    int i = blockIdx.x * blockDim.x + threadIdx.x;
    if (i < E) atomicAdd(&degi[dst[i]], 1);
}

__global__ __launch_bounds__(256) void k_scan1(const int* __restrict__ degi,
                                               int* __restrict__ bsum) {
    __shared__ int red[256];
    int t = threadIdx.x;
    int q = blockIdx.x * 256 + t;
    int s = 0;
    if (q * 4 + 3 < N_NODES) {
        int4 v = reinterpret_cast<const int4*>(degi)[q];
        s = v.x + v.y + v.z + v.w;
    } else {
        for (int j = q * 4; j < min(q * 4 + 4, N_NODES); j++) s += degi[j];
    }
    red[t] = s;
    __syncthreads();
    for (int off = 128; off > 0; off >>= 1) {
        if (t < off) red[t] += red[t + off];
        __syncthreads();
    }
    if (t == 0) bsum[blockIdx.x] = red[0];
}

__global__ __launch_bounds__(64) void k_scan2(const int* __restrict__ bsum,
                                              int* __restrict__ boff) {
    int lane = threadIdx.x;
    int v = (lane < SCAN_BLK) ? bsum[lane] : 0;
    int orig = v;
    for (int off = 1; off < 64; off <<= 1) {
        int w = __shfl_up(v, off, 64);
        if (lane >= off) v += w;
    }
    if (lane < SCAN_BLK) boff[lane] = v - orig;
}

__global__ __launch_bounds__(256) void k_scan3(const int* __restrict__ degi,
                                               const int* __restrict__ boff,
                                               int* __restrict__ rowoff,
                                               int* __restrict__ cur,
                                               float* __restrict__ dis) {
    __shared__ int sums[256];
    int t = threadIdx.x;
    int q = blockIdx.x * 256 + t;
    int d[4] = {0, 0, 0, 0};
    if (q * 4 + 3 < N_NODES) {
        int4 v = reinterpret_cast<const int4*>(degi)[q];
        d[0] = v.x; d[1] = v.y; d[2] = v.z; d[3] = v.w;
    } else {
        for (int j = 0; j < 4; j++)
            if (q * 4 + j < N_NODES) d[j] = degi[q * 4 + j];
    }
    int tsum = d[0] + d[1] + d[2] + d[3];
    sums[t] = tsum;
    __syncthreads();
    for (int off = 1; off < 256; off <<= 1) {
        int v = (t >= off) ? sums[t - off] : 0;
        __syncthreads();
        sums[t] += v;
        __syncthreads();
    }
    int run = boff[blockIdx.x] + sums[t] - tsum;
#pragma unroll
    for (int j = 0; j < 4; j++) {
        int i = q * 4 + j;
        if (i < N_NODES) {
            rowoff[i] = run;
            dis[i] = rsqrtf((float)d[j] + 1.0f);
            cur[i] = 0;
            run += d[j];
            if (i == N_NODES - 1) rowoff[N_NODES] = run;
        }
    }
}

__global__ void k_bucket(const int* __restrict__ src, const int* __restrict__ dst,
                         const int* __restrict__ rowoff, int* __restrict__ cur,
                         int* __restrict__ esrc, int E) {
    int e = blockIdx.x * blockDim.x + threadIdx.x;
    if (e >= E) return;
    int s = src[e], d = dst[e];
    int pos = rowoff[d] + atomicAdd(&cur[d], 1);
    esrc[pos] = s;
}

// W1 [512][96] f32 -> WbT [96][512] bf16
__global__ __launch_bounds__(256) void k_cvtW(const float* __restrict__ W,
                                              unsigned short* __restrict__ WbT) {
    int idx = blockIdx.x * 256 + threadIdx.x;
    if (idx >= NH * NIN) return;
    int n = idx >> 9;
    int k = idx & 511;
    WbT[idx] = f2bf(W[(size_t)k * NH + n]);
}

// h' = (x @ W1) * dis[row], bf16 MFMA 16x16x32. BM=64 (4 waves x 16 rows),
// BK=128 -> 4 iterations, 24 MFMA/wave/iter. LDS rows 256 B, 16 slots of 16 B,
// XOR key (row&7): in-row bijective, fragment reads 2 rows/bank-quad = free.
// Output hb is bf16 [N][96].
#define GBM 64
__global__ __launch_bounds__(256) void k_gemm1(const float* __restrict__ x,
                                               const unsigned short* __restrict__ WbT,
                                               const float* __restrict__ dis,
                                               unsigned short* __restrict__ hb, int M) {
    __shared__ __align__(16) char lAs[64 * 256];   // 16 KB
    __shared__ __align__(16) char lBs[96 * 256];   // 24 KB
    int tid = threadIdx.x;
    int lane = tid & 63;
    int w = tid >> 6;
    int m0 = blockIdx.x * GBM;

    float4 gxa[4], gxb[4];   // A stage: 4 slots/thread (r=idx>>4, s=idx&15)
    uint4 gw[6];             // B stage: 6 slots/thread (n=idx>>4, s=idx&15)

    // ---- stage tile 0 (kb = 0) ----
#pragma unroll
    for (int it = 0; it < 4; ++it) {
        int idx = it * 256 + tid;
        int r = idx >> 4, s = idx & 15;
        const float* p = x + (size_t)min(m0 + r, M - 1) * NIN + s * 8;
        gxa[it] = *reinterpret_cast<const float4*>(p);
        gxb[it] = *reinterpret_cast<const float4*>(p + 4);
    }
#pragma unroll
    for (int it = 0; it < 6; ++it) {
        int idx = it * 256 + tid;
        int n = idx >> 4, s = idx & 15;
        gw[it] = *reinterpret_cast<const uint4*>(WbT + (size_t)n * NIN + s * 8);
    }

    f32x4 acc[6];
#pragma unroll
    for (int nt = 0; nt < 6; ++nt)
#pragma unroll
        for (int i = 0; i < 4; ++i) acc[nt][i] = 0.f;

    int l15 = lane & 15, hi = lane >> 4, key = lane & 7;
    const char* abase = lAs + (w * 16 + l15) * 256;

    for (int kc = 0; kc < 4; ++kc) {       // 4 x BK=128
        __syncthreads();
#pragma unroll
        for (int it = 0; it < 4; ++it) {
            int idx = it * 256 + tid;
            int r = idx >> 4, s = idx & 15;
            uint4 ap;
            ap.x = (unsigned)f2bf(gxa[it].x) | ((unsigned)f2bf(gxa[it].y) << 16);
            ap.y = (unsigned)f2bf(gxa[it].z) | ((unsigned)f2bf(gxa[it].w) << 16);
            ap.z = (unsigned)f2bf(gxb[it].x) | ((unsigned)f2bf(gxb[it].y) << 16);
            ap.w = (unsigned)f2bf(gxb[it].z) | ((unsigned)f2bf(gxb[it].w) << 16);
            *reinterpret_cast<uint4*>(lAs + r * 256 + ((s ^ (r & 7)) << 4)) = ap;
        }
#pragma unroll
        for (int it = 0; it < 6; ++it) {
            int idx = it * 256 + tid;
            int n = idx >> 4, s = idx & 15;
            *reinterpret_cast<uint4*>(lBs + n * 256 + ((s ^ (n & 7)) << 4)) = gw[it];
        }
        __syncthreads();

        if (kc + 1 < 4) {                  // prefetch next K-tile
            int kb = (kc + 1) * 128;
#pragma unroll
            for (int it = 0; it < 4; ++it) {
                int idx = it * 256 + tid;
                int r = idx >> 4, s = idx & 15;
                const float* p = x + (size_t)min(m0 + r, M - 1) * NIN + kb + s * 8;
                gxa[it] = *reinterpret_cast<const float4*>(p);
                gxb[it] = *reinterpret_cast<const float4*>(p + 4);
            }
#pragma unroll
            for (int it = 0; it < 6; ++it) {
                int idx = it * 256 + tid;
                int n = idx >> 4, s = idx & 15;
                gw[it] = *reinterpret_cast<const uint4*>(WbT + (size_t)n * NIN + kb + s * 8);
            }
        }

#pragma unroll
        for (int kk = 0; kk < 4; ++kk) {
            int off = ((kk * 4 + hi) ^ key) << 4;
            short8v a = *reinterpret_cast<const short8v*>(abase + off);
#pragma unroll
            for (int nt = 0; nt < 6; ++nt) {
                short8v b = *reinterpret_cast<const short8v*>(
                    lBs + (nt * 16 + l15) * 256 + off);
                acc[nt] = __builtin_amdgcn_mfma_f32_16x16x32_bf16(a, b, acc[nt], 0, 0, 0);
            }
        }
    }

    // C: row=(lane>>4)*4+reg, col=lane&15 (m89-verified); fuse dis scale, write bf16
    int rbase = m0 + w * 16 + hi * 4;
#pragma unroll
    for (int r = 0; r < 4; ++r) {
        int row = rbase + r;
        if (row < M) {
            float dv = dis[row];
            unsigned short* op = hb + (size_t)row * NH + l15;
#pragma unroll
            for (int nt = 0; nt < 6; ++nt) op[nt * 16] = f2bf(acc[nt][r] * dv);
        }
    }
}

// gather layer 1 (bf16 rows, 192B): hid = relu((sum h'[s] + h'[i]) * dis + b1)
__global__ __launch_bounds__(256) void k_gather1(const ushort4* __restrict__ hb4,
                                                 const int* __restrict__ rowoff,
                                                 const int* __restrict__ esrc,
                                                 const float* __restrict__ dis,
                                                 const float* __restrict__ b1,
                                                 ushort4* __restrict__ hid4) {
    int tid = threadIdx.x;
    int node = blockIdx.x * 8 + (tid >> 5);
    int c = tid & 31;
    if (node >= N_NODES) return;
    int p0 = rowoff[node], p1 = rowoff[node + 1];
    bool act = (c < 24);
    float ax = 0.f, ay = 0.f, az = 0.f, aw = 0.f;
    for (int pb = p0; pb < p1; pb += 32) {
        int nb = min(32, p1 - pb);
        int sv = (c < nb) ? esrc[pb + c] : 0;
#pragma unroll 4
        for (int j = 0; j < nb; j++) {
            int s = __shfl(sv, j, 32);
            if (act) {
                ushort4 v = hb4[(size_t)s * 24 + c];
                ax += bf2f(v.x); ay += bf2f(v.y); az += bf2f(v.z); aw += bf2f(v.w);
            }
        }
    }
    if (act) {
        float dv = dis[node];
        ushort4 hv = hb4[(size_t)node * 24 + c];
        float4 bv = reinterpret_cast<const float4*>(b1)[c];
        float rx = fmaxf((ax + bf2f(hv.x)) * dv + bv.x, 0.f);
        float ry = fmaxf((ay + bf2f(hv.y)) * dv + bv.y, 0.f);
        float rz = fmaxf((az + bf2f(hv.z)) * dv + bv.z, 0.f);
        float rw = fmaxf((aw + bf2f(hv.w)) * dv + bv.w, 0.f);
        ushort4 o;
        o.x = f2bf(rx); o.y = f2bf(ry); o.z = f2bf(rz); o.w = f2bf(rw);
        hid4[(size_t)node * 24 + c] = o;
    }
}

// h23' = (hid @ [W_mu|W_logstd]) * dis[row]; hid bf16 in, h23 bf16 out
__global__ __launch_bounds__(256) void k_gemm2(const unsigned short* __restrict__ hid,
                                               const float* __restrict__ Wmu,
                                               const float* __restrict__ Wls,
                                               const float* __restrict__ dis,
                                               unsigned int* __restrict__ h23, int M) {
    __shared__ float wl[NH][NH2];
    int tid = threadIdx.x;
#pragma unroll
    for (int it = 0; it < 6; ++it) {
        int idx = it * 256 + tid;
        int k = idx >> 4;
        int c4 = idx & 15;
        float4 v;
        if (c4 < 8) v = *reinterpret_cast<const float4*>(&Wmu[k * NL + c4 * 4]);
        else        v = *reinterpret_cast<const float4*>(&Wls[k * NL + (c4 - 8) * 4]);
        *reinterpret_cast<float4*>(&wl[k][c4 * 4]) = v;
    }
    __syncthreads();
    int row = blockIdx.x * 128 + (tid >> 1);
    int half = tid & 1;
    if (row >= M) return;
    float acc[NL];
#pragma unroll
    for (int j = 0; j < NL; j++) acc[j] = 0.f;
    const uint4* hr = reinterpret_cast<const uint4*>(hid + (size_t)row * NH);
#pragma unroll 3
    for (int kq = 0; kq < 12; kq++) {      // 12 x 8 bf16 = 96 k
        uint4 hv = hr[kq];
        unsigned hu[4] = {hv.x, hv.y, hv.z, hv.w};
#pragma unroll
        for (int p = 0; p < 4; p++) {
            float hlo = __uint_as_float(hu[p] << 16);
            float hhi = __uint_as_float(hu[p] & 0xFFFF0000u);
            const float* w0 = &wl[kq * 8 + p * 2][half * NL];
            const float* w1 = &wl[kq * 8 + p * 2 + 1][half * NL];
#pragma unroll
            for (int j = 0; j < NL; j++) acc[j] = fmaf(hlo, w0[j], acc[j]);
#pragma unroll
            for (int j = 0; j < NL; j++) acc[j] = fmaf(hhi, w1[j], acc[j]);
        }
    }
    float dv = dis[row];
    uint4* o4 = reinterpret_cast<uint4*>(h23 + (size_t)row * (NH2 / 2) + half * 16);
#pragma unroll
    for (int j4 = 0; j4 < 4; j4++) {
        uint4 o;
        o.x = (unsigned)f2bf(acc[j4 * 8 + 0] * dv) | ((unsigned)f2bf(acc[j4 * 8 + 1] * dv) << 16);
        o.y = (unsigned)f2bf(acc[j4 * 8 + 2] * dv) | ((unsigned)f2bf(acc[j4 * 8 + 3] * dv) << 16);
        o.z = (unsigned)f2bf(acc[j4 * 8 + 4] * dv) | ((unsigned)f2bf(acc[j4 * 8 + 5] * dv) << 16);
        o.w = (unsigned)f2bf(acc[j4 * 8 + 6] * dv) | ((unsigned)f2bf(acc[j4 * 8 + 7] * dv) << 16);
        o4[j4] = o;
    }
}

// gather layer 2 (bf16 rows, 128B): out = (sum h23'[s] + h23'[i]) * dis + bias
__global__ __launch_bounds__(256) void k_gather2(const ushort4* __restrict__ hb4,
                                                 const int* __restrict__ rowoff,
                                                 const int* __restrict__ esrc,
                                                 const float* __restrict__ dis,
                                                 const float* __restrict__ bmu,
                                                 const float* __restrict__ bls,
                                                 float4* __restrict__ out4) {
    int tid = threadIdx.x;
    int node = blockIdx.x * 16 + (tid >> 4);
    int c = tid & 15;
    if (node >= N_NODES) return;
    int p0 = rowoff[node], p1 = rowoff[node + 1];
    float ax = 0.f, ay = 0.f, az = 0.f, aw = 0.f;
    for (int pb = p0; pb < p1; pb += 16) {
        int nb = min(16, p1 - pb);
        int sv = (c < nb) ? esrc[pb + c] : 0;
#pragma unroll 4
        for (int j = 0; j < nb; j++) {
            int s = __shfl(sv, j, 16);
            ushort4 v = hb4[(size_t)s * 16 + c];
            ax += bf2f(v.x); ay += bf2f(v.y); az += bf2f(v.z); aw += bf2f(v.w);
        }
    }
    float dv = dis[node];
    ushort4 hv = hb4[(size_t)node * 16 + c];
    float4 bv = (c < 8) ? reinterpret_cast<const float4*>(bmu)[c]
                        : reinterpret_cast<const float4*>(bls)[c - 8];
    float4 o;
    o.x = (ax + bf2f(hv.x)) * dv + bv.x;
    o.y = (ay + bf2f(hv.y)) * dv + bv.y;
    o.z = (az + bf2f(hv.z)) * dv + bv.z;
    o.w = (aw + bf2f(hv.w)) * dv + bv.w;
    if (c < 8) out4[(size_t)node * 8 + c] = o;
    else       out4[(size_t)N_NODES * 8 + (size_t)node * 8 + (c - 8)] = o;
}

extern "C" void kernel_launch(void* const* d_in, const int* in_sizes, int n_in,
                              void* d_out, int out_size, void* d_ws, size_t ws_size,
                              hipStream_t stream) {
    const float* x   = (const float*)d_in[0];
    const float* W1  = (const float*)d_in[1];
    const float* b1  = (const float*)d_in[2];
    const float* Wmu = (const float*)d_in[3];
    const float* bmu = (const float*)d_in[4];
    const float* Wls = (const float*)d_in[5];
    const float* bls = (const float*)d_in[6];
    const int*   ei  = (const int*)d_in[7];
    int E = in_sizes[7] / 2;
    const int* src  = ei;
    const int* dstp = ei + E;

    char* w = (char*)d_ws;
    int* degi    = (int*)w;            w += (size_t)N_NODES * 4;
    int* cur     = (int*)w;            w += (size_t)N_NODES * 4;
    int* rowoff  = (int*)w;            w += ((size_t)N_NODES + 4) * 4;
    float* dis   = (float*)w;          w += (size_t)N_NODES * 4;
    int* bsum    = (int*)w;            w += 64 * 4;
    int* boff    = (int*)w;            w += 64 * 4;
    int* esrc    = (int*)w;            w += (size_t)E * 4;
    unsigned short* WbT = (unsigned short*)w;   w += (size_t)NH * NIN * 2;
    unsigned short* hbuf = (unsigned short*)w;  w += (size_t)N_NODES * NH * 2;   // h' bf16
    unsigned short* hid  = (unsigned short*)w;  w += (size_t)N_NODES * NH * 2;   // hidden bf16
    unsigned int*   h23  = (unsigned int*)w;    w += (size_t)N_NODES * (NH2 / 2) * 4; // bf16 x2

    k_cvtW<<<(NH * NIN + 255) / 256, 256, 0, stream>>>(W1, WbT);

    k_zero_int<<<(N_NODES + 255) / 256, 256, 0, stream>>>(degi, N_NODES);
    k_degi<<<(E + 255) / 256, 256, 0, stream>>>(dstp, degi, E);
    k_scan1<<<SCAN_BLK, 256, 0, stream>>>(degi, bsum);
    k_scan2<<<1, 64, 0, stream>>>(bsum, boff);
    k_scan3<<<SCAN_BLK, 256, 0, stream>>>(degi, boff, rowoff, cur, dis);
    k_bucket<<<(E + 255) / 256, 256, 0, stream>>>(src, dstp, rowoff, cur, esrc, E);

    k_gemm1<<<(N_NODES + GBM - 1) / GBM, 256, 0, stream>>>(x, WbT, dis, hbuf, N_NODES);

    k_gather1<<<(N_NODES + 7) / 8, 256, 0, stream>>>(
        (const ushort4*)hbuf, rowoff, esrc, dis, b1, (ushort4*)hid);

    k_gemm2<<<(N_NODES + 127) / 128, 256, 0, stream>>>(hid, Wmu, Wls, dis, h23, N_NODES);

    k_gather2<<<(N_NODES + 15) / 16, 256, 0, stream>>>(
        (const ushort4*)h23, rowoff, esrc, dis, bmu, bls, (float4*)d_out);
}

// Round 11
// 235.675 us; speedup vs baseline: 1.0357x; 1.0357x over previous
//
#include <hip/hip_runtime.h>

#define N_NODES 50000
#define NIN 512
#define NH 96
#define NL 32
#define NH2 64

#define SCAN_BLK 49

typedef __attribute__((ext_vector_type(8))) short short8v;   // 8 bf16 (4 VGPR)
typedef __attribute__((ext_vector_type(4))) float f32x4;

__device__ __forceinline__ unsigned short f2bf(float f) {    // RNE f32->bf16
    unsigned u = __float_as_uint(f);
    u = (u + 0x7FFFu + ((u >> 16) & 1u)) >> 16;
    return (unsigned short)u;
}
__device__ __forceinline__ float bf2f(unsigned short h) {
    return __uint_as_float((unsigned)h << 16);
}

// fused: WbT = W1^T bf16 [96][512]; W2T = [Wmu|Wls]^T bf16 [64][96]; degi = 0
__global__ __launch_bounds__(256) void k_prep(const float* __restrict__ W1,
                                              const float* __restrict__ Wmu,
                                              const float* __restrict__ Wls,
                                              unsigned short* __restrict__ WbT,
                                              unsigned short* __restrict__ W2T,
                                              int* __restrict__ degi) {
    int idx = blockIdx.x * 256 + threadIdx.x;
    if (idx < NH * NIN) {
        int n = idx >> 9, k = idx & 511;
        WbT[idx] = f2bf(W1[(size_t)k * NH + n]);
    } else if (idx < NH * NIN + NH2 * NH) {
        int j = idx - NH * NIN;
        int n = j / NH, k = j - n * NH;          // n 0..63, k 0..95
        float v = (n < NL) ? Wmu[k * NL + n] : Wls[k * NL + (n - NL)];
        W2T[j] = f2bf(v);
    }
    if (idx < N_NODES) degi[idx] = 0;
}

__global__ void k_degi(const int* __restrict__ dst, int* __restrict__ degi, int E) {
    int i = blockIdx.x * blockDim.x + threadIdx.x;
    if (i < E) atomicAdd(&degi[dst[i]], 1);
}

__global__ __launch_bounds__(256) void k_scan1(const int* __restrict__ degi,
                                               int* __restrict__ bsum) {
    __shared__ int red[256];
    int t = threadIdx.x;
    int q = blockIdx.x * 256 + t;
    int s = 0;
    if (q * 4 + 3 < N_NODES) {
        int4 v = reinterpret_cast<const int4*>(degi)[q];
        s = v.x + v.y + v.z + v.w;
    } else {
        for (int j = q * 4; j < min(q * 4 + 4, N_NODES); j++) s += degi[j];
    }
    red[t] = s;
    __syncthreads();
    for (int off = 128; off > 0; off >>= 1) {
        if (t < off) red[t] += red[t + off];
        __syncthreads();
    }
    if (t == 0) bsum[blockIdx.x] = red[0];
}

__global__ __launch_bounds__(64) void k_scan2(const int* __restrict__ bsum,
                                              int* __restrict__ boff) {
    int lane = threadIdx.x;
    int v = (lane < SCAN_BLK) ? bsum[lane] : 0;
    int orig = v;
    for (int off = 1; off < 64; off <<= 1) {
        int w = __shfl_up(v, off, 64);
        if (lane >= off) v += w;
    }
    if (lane < SCAN_BLK) boff[lane] = v - orig;
}

__global__ __launch_bounds__(256) void k_scan3(const int* __restrict__ degi,
                                               const int* __restrict__ boff,
                                               int* __restrict__ rowoff,
                                               int* __restrict__ cur,
                                               float* __restrict__ dis) {
    __shared__ int sums[256];
    int t = threadIdx.x;
    int q = blockIdx.x * 256 + t;
    int d[4] = {0, 0, 0, 0};
    if (q * 4 + 3 < N_NODES) {
        int4 v = reinterpret_cast<const int4*>(degi)[q];
        d[0] = v.x; d[1] = v.y; d[2] = v.z; d[3] = v.w;
    } else {
        for (int j = 0; j < 4; j++)
            if (q * 4 + j < N_NODES) d[j] = degi[q * 4 + j];
    }
    int tsum = d[0] + d[1] + d[2] + d[3];
    sums[t] = tsum;
    __syncthreads();
    for (int off = 1; off < 256; off <<= 1) {
        int v = (t >= off) ? sums[t - off] : 0;
        __syncthreads();
        sums[t] += v;
        __syncthreads();
    }
    int run = boff[blockIdx.x] + sums[t] - tsum;
#pragma unroll
    for (int j = 0; j < 4; j++) {
        int i = q * 4 + j;
        if (i < N_NODES) {
            rowoff[i] = run;
            dis[i] = rsqrtf((float)d[j] + 1.0f);
            cur[i] = 0;
            run += d[j];
            if (i == N_NODES - 1) rowoff[N_NODES] = run;
        }
    }
}

__global__ void k_bucket(const int* __restrict__ src, const int* __restrict__ dst,
                         const int* __restrict__ rowoff, int* __restrict__ cur,
                         int* __restrict__ esrc, int E) {
    int e = blockIdx.x * blockDim.x + threadIdx.x;
    if (e >= E) return;
    int s = src[e], d = dst[e];
    int pos = rowoff[d] + atomicAdd(&cur[d], 1);
    esrc[pos] = s;
}

// h' = (x @ W1) * dis[row], bf16 MFMA 16x16x32, ZERO LDS / ZERO barriers.
// Per-lane direct fragment loads: A: x[m0+w*16+(l&15)][kc*32+hi*8 ..+8] (32B f32,
// wave-coalesced into 128B segments); B: WbT fragment 16B (L2-hot, 96KB total).
// Same (refcheck-verified) fragment index math as the round-9 LDS kernel.
#define GBM 64
__global__ __launch_bounds__(256) void k_gemm1(const float* __restrict__ x,
                                               const unsigned short* __restrict__ WbT,
                                               const float* __restrict__ dis,
                                               unsigned short* __restrict__ hb, int M) {
    int tid = threadIdx.x;
    int lane = tid & 63, w = tid >> 6;
    int l15 = lane & 15, hi = lane >> 4;
    int m0 = blockIdx.x * GBM;
    int row = m0 + w * 16 + l15;
    const float* ap = x + (size_t)min(row, M - 1) * NIN + hi * 8;
    const unsigned short* bp = WbT + (size_t)l15 * NIN + hi * 8;

    f32x4 acc[6];
#pragma unroll
    for (int nt = 0; nt < 6; ++nt)
#pragma unroll
        for (int i = 0; i < 4; ++i) acc[nt][i] = 0.f;

#pragma unroll 4
    for (int kc = 0; kc < NIN / 32; ++kc) {
        float4 a0 = *reinterpret_cast<const float4*>(ap + kc * 32);
        float4 a1 = *reinterpret_cast<const float4*>(ap + kc * 32 + 4);
        union { short8v v; unsigned u[4]; } A;
        A.u[0] = (unsigned)f2bf(a0.x) | ((unsigned)f2bf(a0.y) << 16);
        A.u[1] = (unsigned)f2bf(a0.z) | ((unsigned)f2bf(a0.w) << 16);
        A.u[2] = (unsigned)f2bf(a1.x) | ((unsigned)f2bf(a1.y) << 16);
        A.u[3] = (unsigned)f2bf(a1.z) | ((unsigned)f2bf(a1.w) << 16);
#pragma unroll
        for (int nt = 0; nt < 6; ++nt) {
            short8v bv = *reinterpret_cast<const short8v*>(bp + nt * 16 * NIN + kc * 32);
            acc[nt] = __builtin_amdgcn_mfma_f32_16x16x32_bf16(A.v, bv, acc[nt], 0, 0, 0);
        }
    }

    // C: row=(lane>>4)*4+reg, col=lane&15 (m89-verified); fuse dis scale, bf16 out
    int rbase = m0 + w * 16 + hi * 4;
#pragma unroll
    for (int r = 0; r < 4; ++r) {
        int orow = rbase + r;
        if (orow < M) {
            float dv = dis[orow];
            unsigned short* op = hb + (size_t)orow * NH + l15;
#pragma unroll
            for (int nt = 0; nt < 6; ++nt) op[nt * 16] = f2bf(acc[nt][r] * dv);
        }
    }
}

// gather layer 1 (bf16 rows, 192B): hid = relu((sum h'[s] + h'[i]) * dis + b1)
__global__ __launch_bounds__(256) void k_gather1(const ushort4* __restrict__ hb4,
                                                 const int* __restrict__ rowoff,
                                                 const int* __restrict__ esrc,
                                                 const float* __restrict__ dis,
                                                 const float* __restrict__ b1,
                                                 ushort4* __restrict__ hid4) {
    int tid = threadIdx.x;
    int node = blockIdx.x * 8 + (tid >> 5);
    int c = tid & 31;
    if (node >= N_NODES) return;
    int p0 = rowoff[node], p1 = rowoff[node + 1];
    bool act = (c < 24);
    float ax = 0.f, ay = 0.f, az = 0.f, aw = 0.f;
    for (int pb = p0; pb < p1; pb += 32) {
        int nb = min(32, p1 - pb);
        int sv = (c < nb) ? esrc[pb + c] : 0;
#pragma unroll 4
        for (int j = 0; j < nb; j++) {
            int s = __shfl(sv, j, 32);
            if (act) {
                ushort4 v = hb4[(size_t)s * 24 + c];
                ax += bf2f(v.x); ay += bf2f(v.y); az += bf2f(v.z); aw += bf2f(v.w);
            }
        }
    }
    if (act) {
        float dv = dis[node];
        ushort4 hv = hb4[(size_t)node * 24 + c];
        float4 bv = reinterpret_cast<const float4*>(b1)[c];
        ushort4 o;
        o.x = f2bf(fmaxf((ax + bf2f(hv.x)) * dv + bv.x, 0.f));
        o.y = f2bf(fmaxf((ay + bf2f(hv.y)) * dv + bv.y, 0.f));
        o.z = f2bf(fmaxf((az + bf2f(hv.z)) * dv + bv.z, 0.f));
        o.w = f2bf(fmaxf((aw + bf2f(hv.w)) * dv + bv.w, 0.f));
        hid4[(size_t)node * 24 + c] = o;
    }
}

// h23' = (hid @ W2) * dis[row], bf16 MFMA, LDS-free. hid bf16 [N][96],
// W2T bf16 [64][96] (12KB, L1-hot). 3 k-steps x 4 n-tiles = 12 MFMA/wave.
__global__ __launch_bounds__(256) void k_gemm2(const unsigned short* __restrict__ hid,
                                               const unsigned short* __restrict__ W2T,
                                               const float* __restrict__ dis,
                                               unsigned short* __restrict__ h23, int M) {
    int tid = threadIdx.x;
    int lane = tid & 63, w = tid >> 6;
    int l15 = lane & 15, hi = lane >> 4;
    int m0 = blockIdx.x * GBM;
    int row = m0 + w * 16 + l15;
    const unsigned short* ap = hid + (size_t)min(row, M - 1) * NH + hi * 8;
    const unsigned short* bp = W2T + (size_t)l15 * NH + hi * 8;

    f32x4 acc[4];
#pragma unroll
    for (int nt = 0; nt < 4; ++nt)
#pragma unroll
        for (int i = 0; i < 4; ++i) acc[nt][i] = 0.f;

#pragma unroll
    for (int kc = 0; kc < 3; ++kc) {
        short8v av = *reinterpret_cast<const short8v*>(ap + kc * 32);
#pragma unroll
        for (int nt = 0; nt < 4; ++nt) {
            short8v bv = *reinterpret_cast<const short8v*>(bp + nt * 16 * NH + kc * 32);
            acc[nt] = __builtin_amdgcn_mfma_f32_16x16x32_bf16(av, bv, acc[nt], 0, 0, 0);
        }
    }

    int rbase = m0 + w * 16 + hi * 4;
#pragma unroll
    for (int r = 0; r < 4; ++r) {
        int orow = rbase + r;
        if (orow < M) {
            float dv = dis[orow];
            unsigned short* op = h23 + (size_t)orow * NH2 + l15;
#pragma unroll
            for (int nt = 0; nt < 4; ++nt) op[nt * 16] = f2bf(acc[nt][r] * dv);
        }
    }
}

// gather layer 2 (bf16 rows, 128B): out = (sum h23'[s] + h23'[i]) * dis + bias
__global__ __launch_bounds__(256) void k_gather2(const ushort4* __restrict__ hb4,
                                                 const int* __restrict__ rowoff,
                                                 const int* __restrict__ esrc,
                                                 const float* __restrict__ dis,
                                                 const float* __restrict__ bmu,
                                                 const float* __restrict__ bls,
                                                 float4* __restrict__ out4) {
    int tid = threadIdx.x;
    int node = blockIdx.x * 16 + (tid >> 4);
    int c = tid & 15;
    if (node >= N_NODES) return;
    int p0 = rowoff[node], p1 = rowoff[node + 1];
    float ax = 0.f, ay = 0.f, az = 0.f, aw = 0.f;
    for (int pb = p0; pb < p1; pb += 16) {
        int nb = min(16, p1 - pb);
        int sv = (c < nb) ? esrc[pb + c] : 0;
#pragma unroll 4
        for (int j = 0; j < nb; j++) {
            int s = __shfl(sv, j, 16);
            ushort4 v = hb4[(size_t)s * 16 + c];
            ax += bf2f(v.x); ay += bf2f(v.y); az += bf2f(v.z); aw += bf2f(v.w);
        }
    }
    float dv = dis[node];
    ushort4 hv = hb4[(size_t)node * 16 + c];
    float4 bv = (c < 8) ? reinterpret_cast<const float4*>(bmu)[c]
                        : reinterpret_cast<const float4*>(bls)[c - 8];
    float4 o;
    o.x = (ax + bf2f(hv.x)) * dv + bv.x;
    o.y = (ay + bf2f(hv.y)) * dv + bv.y;
    o.z = (az + bf2f(hv.z)) * dv + bv.z;
    o.w = (aw + bf2f(hv.w)) * dv + bv.w;
    if (c < 8) out4[(size_t)node * 8 + c] = o;
    else       out4[(size_t)N_NODES * 8 + (size_t)node * 8 + (c - 8)] = o;
}

extern "C" void kernel_launch(void* const* d_in, const int* in_sizes, int n_in,
                              void* d_out, int out_size, void* d_ws, size_t ws_size,
                              hipStream_t stream) {
    const float* x   = (const float*)d_in[0];
    const float* W1  = (const float*)d_in[1];
    const float* b1  = (const float*)d_in[2];
    const float* Wmu = (const float*)d_in[3];
    const float* bmu = (const float*)d_in[4];
    const float* Wls = (const float*)d_in[5];
    const float* bls = (const float*)d_in[6];
    const int*   ei  = (const int*)d_in[7];
    int E = in_sizes[7] / 2;
    const int* src  = ei;
    const int* dstp = ei + E;

    char* w = (char*)d_ws;
    int* degi    = (int*)w;            w += (size_t)N_NODES * 4;
    int* cur     = (int*)w;            w += (size_t)N_NODES * 4;
    int* rowoff  = (int*)w;            w += ((size_t)N_NODES + 4) * 4;
    float* dis   = (float*)w;          w += (size_t)N_NODES * 4;
    int* bsum    = (int*)w;            w += 64 * 4;
    int* boff    = (int*)w;            w += 64 * 4;
    int* esrc    = (int*)w;            w += (size_t)E * 4;
    unsigned short* WbT  = (unsigned short*)w;  w += (size_t)NH * NIN * 2;
    unsigned short* W2T  = (unsigned short*)w;  w += (size_t)NH2 * NH * 2;
    unsigned short* hbuf = (unsigned short*)w;  w += (size_t)N_NODES * NH * 2;
    unsigned short* hid  = (unsigned short*)w;  w += (size_t)N_NODES * NH * 2;
    unsigned short* h23  = (unsigned short*)w;  w += (size_t)N_NODES * NH2 * 2;

    int prep_n = NH * NIN + NH2 * NH;          // 55296 >= 50000 (degi zero)
    k_prep<<<(prep_n + 255) / 256, 256, 0, stream>>>(W1, Wmu, Wls, WbT, W2T, degi);

    k_degi<<<(E + 255) / 256, 256, 0, stream>>>(dstp, degi, E);
    k_scan1<<<SCAN_BLK, 256, 0, stream>>>(degi, bsum);
    k_scan2<<<1, 64, 0, stream>>>(bsum, boff);
    k_scan3<<<SCAN_BLK, 256, 0, stream>>>(degi, boff, rowoff, cur, dis);
    k_bucket<<<(E + 255) / 256, 256, 0, stream>>>(src, dstp, rowoff, cur, esrc, E);

    k_gemm1<<<(N_NODES + GBM - 1) / GBM, 256, 0, stream>>>(x, WbT, dis, hbuf, N_NODES);

    k_gather1<<<(N_NODES + 7) / 8, 256, 0, stream>>>(
        (const ushort4*)hbuf, rowoff, esrc, dis, b1, (ushort4*)hid);

    k_gemm2<<<(N_NODES + GBM - 1) / GBM, 256, 0, stream>>>(hid, W2T, dis, h23, N_NODES);

    k_gather2<<<(N_NODES + 15) / 16, 256, 0, stream>>>(
        (const ushort4*)h23, rowoff, esrc, dis, bmu, bls, (float4*)d_out);
}

// Round 12
// 201.832 us; speedup vs baseline: 1.2093x; 1.1677x over previous
//
#include <hip/hip_runtime.h>

#define N_NODES 50000
#define NIN 512
#define NH 96
#define NL 32
#define NH2 64

#define SCAN_BLK 49

typedef __attribute__((ext_vector_type(8))) short short8v;   // 8 bf16 (4 VGPR)
typedef __attribute__((ext_vector_type(4))) float f32x4;

__device__ __forceinline__ unsigned short f2bf(float f) {    // RNE f32->bf16
    unsigned u = __float_as_uint(f);
    u = (u + 0x7FFFu + ((u >> 16) & 1u)) >> 16;
    return (unsigned short)u;
}
__device__ __forceinline__ float bf2f(unsigned short h) {
    return __uint_as_float((unsigned)h << 16);
}

// fused: WbT = W1^T bf16 [96][512]; W2T = [Wmu|Wls]^T bf16 [64][96]; degi = 0
__global__ __launch_bounds__(256) void k_prep(const float* __restrict__ W1,
                                              const float* __restrict__ Wmu,
                                              const float* __restrict__ Wls,
                                              unsigned short* __restrict__ WbT,
                                              unsigned short* __restrict__ W2T,
                                              int* __restrict__ degi) {
    int idx = blockIdx.x * 256 + threadIdx.x;
    if (idx < NH * NIN) {
        int n = idx >> 9, k = idx & 511;
        WbT[idx] = f2bf(W1[(size_t)k * NH + n]);
    } else if (idx < NH * NIN + NH2 * NH) {
        int j = idx - NH * NIN;
        int n = j / NH, k = j - n * NH;
        float v = (n < NL) ? Wmu[k * NL + n] : Wls[k * NL + (n - NL)];
        W2T[j] = f2bf(v);
    }
    if (idx < N_NODES) degi[idx] = 0;
}

__global__ void k_degi(const int* __restrict__ dst, int* __restrict__ degi, int E) {
    int i = blockIdx.x * blockDim.x + threadIdx.x;
    if (i < E) atomicAdd(&degi[dst[i]], 1);
}

__global__ __launch_bounds__(256) void k_scan1(const int* __restrict__ degi,
                                               int* __restrict__ bsum) {
    __shared__ int red[256];
    int t = threadIdx.x;
    int q = blockIdx.x * 256 + t;
    int s = 0;
    if (q * 4 + 3 < N_NODES) {
        int4 v = reinterpret_cast<const int4*>(degi)[q];
        s = v.x + v.y + v.z + v.w;
    } else {
        for (int j = q * 4; j < min(q * 4 + 4, N_NODES); j++) s += degi[j];
    }
    red[t] = s;
    __syncthreads();
    for (int off = 128; off > 0; off >>= 1) {
        if (t < off) red[t] += red[t + off];
        __syncthreads();
    }
    if (t == 0) bsum[blockIdx.x] = red[0];
}

__global__ __launch_bounds__(64) void k_scan2(const int* __restrict__ bsum,
                                              int* __restrict__ boff) {
    int lane = threadIdx.x;
    int v = (lane < SCAN_BLK) ? bsum[lane] : 0;
    int orig = v;
    for (int off = 1; off < 64; off <<= 1) {
        int w = __shfl_up(v, off, 64);
        if (lane >= off) v += w;
    }
    if (lane < SCAN_BLK) boff[lane] = v - orig;
}

__global__ __launch_bounds__(256) void k_scan3(const int* __restrict__ degi,
                                               const int* __restrict__ boff,
                                               int* __restrict__ rowoff,
                                               int* __restrict__ cur,
                                               float* __restrict__ dis) {
    __shared__ int sums[256];
    int t = threadIdx.x;
    int q = blockIdx.x * 256 + t;
    int d[4] = {0, 0, 0, 0};
    if (q * 4 + 3 < N_NODES) {
        int4 v = reinterpret_cast<const int4*>(degi)[q];
        d[0] = v.x; d[1] = v.y; d[2] = v.z; d[3] = v.w;
    } else {
        for (int j = 0; j < 4; j++)
            if (q * 4 + j < N_NODES) d[j] = degi[q * 4 + j];
    }
    int tsum = d[0] + d[1] + d[2] + d[3];
    sums[t] = tsum;
    __syncthreads();
    for (int off = 1; off < 256; off <<= 1) {
        int v = (t >= off) ? sums[t - off] : 0;
        __syncthreads();
        sums[t] += v;
        __syncthreads();
    }
    int run = boff[blockIdx.x] + sums[t] - tsum;
#pragma unroll
    for (int j = 0; j < 4; j++) {
        int i = q * 4 + j;
        if (i < N_NODES) {
            rowoff[i] = run;
            dis[i] = rsqrtf((float)d[j] + 1.0f);
            cur[i] = 0;
            run += d[j];
            if (i == N_NODES - 1) rowoff[N_NODES] = run;
        }
    }
}

__global__ void k_bucket(const int* __restrict__ src, const int* __restrict__ dst,
                         const int* __restrict__ rowoff, int* __restrict__ cur,
                         int* __restrict__ esrc, int E) {
    int e = blockIdx.x * blockDim.x + threadIdx.x;
    if (e >= E) return;
    int s = src[e], d = dst[e];
    int pos = rowoff[d] + atomicAdd(&cur[d], 1);
    esrc[pos] = s;
}

// h' = (x @ W1) * dis[row], bf16 MFMA 16x16x32.
// BM=128 (4 waves x 32 rows = 2 row-tiles each), BK=64, 8 K-tiles.
// LDS rows 128B = 8 slots of 16B, slot ^= (row&7): 8 consecutive rows hit 8
// distinct 4-bank groups -> conflict-free frag reads; staging fully coalesced.
#define GBM 128
__global__ __launch_bounds__(256, 2) void k_gemm1(const float* __restrict__ x,
                                                  const unsigned short* __restrict__ WbT,
                                                  const float* __restrict__ dis,
                                                  unsigned short* __restrict__ hb, int M) {
    __shared__ __align__(16) char lA[128 * 128];   // 16 KB
    __shared__ __align__(16) char lB[96 * 128];    // 12 KB
    int tid = threadIdx.x;
    int lane = tid & 63, w = tid >> 6;
    int l15 = lane & 15, hi = lane >> 4;
    int m0 = blockIdx.x * GBM;

    f32x4 acc[2][6];
#pragma unroll
    for (int rt = 0; rt < 2; ++rt)
#pragma unroll
        for (int nt = 0; nt < 6; ++nt)
#pragma unroll
            for (int i = 0; i < 4; ++i) acc[rt][nt][i] = 0.f;

    int key = l15 & 7;
    int arow0 = (w * 32 + l15) * 128;          // row-tile 0 base (bytes)
    int arow1 = (w * 32 + 16 + l15) * 128;     // row-tile 1

    for (int kt = 0; kt < 8; ++kt) {
        __syncthreads();                        // previous tile's readers done
        // ---- stage A: 1024 slots (128 rows x 8), 4 per thread, coalesced ----
#pragma unroll
        for (int i = 0; i < 4; ++i) {
            int s = i * 256 + tid;
            int r = s >> 3, sl = s & 7;
            const float* p = x + (size_t)min(m0 + r, M - 1) * NIN + kt * 64 + sl * 8;
            float4 a0 = *reinterpret_cast<const float4*>(p);
            float4 a1 = *reinterpret_cast<const float4*>(p + 4);
            uint4 pk;
            pk.x = (unsigned)f2bf(a0.x) | ((unsigned)f2bf(a0.y) << 16);
            pk.y = (unsigned)f2bf(a0.z) | ((unsigned)f2bf(a0.w) << 16);
            pk.z = (unsigned)f2bf(a1.x) | ((unsigned)f2bf(a1.y) << 16);
            pk.w = (unsigned)f2bf(a1.z) | ((unsigned)f2bf(a1.w) << 16);
            *reinterpret_cast<uint4*>(lA + r * 128 + ((sl ^ (r & 7)) << 4)) = pk;
        }
        // ---- stage B: 768 slots (96 rows x 8), 3 per thread, coalesced ----
#pragma unroll
        for (int i = 0; i < 3; ++i) {
            int s = i * 256 + tid;
            int n = s >> 3, sl = s & 7;
            uint4 bv = *reinterpret_cast<const uint4*>(WbT + (size_t)n * NIN + kt * 64 + sl * 8);
            *reinterpret_cast<uint4*>(lB + n * 128 + ((sl ^ (n & 7)) << 4)) = bv;
        }
        __syncthreads();                        // tile ready

#pragma unroll
        for (int kc = 0; kc < 2; ++kc) {
            int off = (((kc * 4 + hi) ^ key) << 4);
            short8v a0 = *reinterpret_cast<const short8v*>(lA + arow0 + off);
            short8v a1 = *reinterpret_cast<const short8v*>(lA + arow1 + off);
#pragma unroll
            for (int nt = 0; nt < 6; ++nt) {
                short8v bv = *reinterpret_cast<const short8v*>(lB + (nt * 16 + l15) * 128 + off);
                acc[0][nt] = __builtin_amdgcn_mfma_f32_16x16x32_bf16(a0, bv, acc[0][nt], 0, 0, 0);
                acc[1][nt] = __builtin_amdgcn_mfma_f32_16x16x32_bf16(a1, bv, acc[1][nt], 0, 0, 0);
            }
        }
    }

    // C: row=(lane>>4)*4+reg, col=lane&15 (m89-verified); fuse dis scale, bf16 out
#pragma unroll
    for (int rt = 0; rt < 2; ++rt) {
        int rbase = m0 + w * 32 + rt * 16 + hi * 4;
#pragma unroll
        for (int r = 0; r < 4; ++r) {
            int orow = rbase + r;
            if (orow < M) {
                float dv = dis[orow];
                unsigned short* op = hb + (size_t)orow * NH + l15;
#pragma unroll
                for (int nt = 0; nt < 6; ++nt) op[nt * 16] = f2bf(acc[rt][nt][r] * dv);
            }
        }
    }
}

// gather layer 1 (bf16 rows, 192B): hid = relu((sum h'[s] + h'[i]) * dis + b1)
__global__ __launch_bounds__(256) void k_gather1(const ushort4* __restrict__ hb4,
                                                 const int* __restrict__ rowoff,
                                                 const int* __restrict__ esrc,
                                                 const float* __restrict__ dis,
                                                 const float* __restrict__ b1,
                                                 ushort4* __restrict__ hid4) {
    int tid = threadIdx.x;
    int node = blockIdx.x * 8 + (tid >> 5);
    int c = tid & 31;
    if (node >= N_NODES) return;
    int p0 = rowoff[node], p1 = rowoff[node + 1];
    bool act = (c < 24);
    float ax = 0.f, ay = 0.f, az = 0.f, aw = 0.f;
    for (int pb = p0; pb < p1; pb += 32) {
        int nb = min(32, p1 - pb);
        int sv = (c < nb) ? esrc[pb + c] : 0;
#pragma unroll 4
        for (int j = 0; j < nb; j++) {
            int s = __shfl(sv, j, 32);
            if (act) {
                ushort4 v = hb4[(size_t)s * 24 + c];
                ax += bf2f(v.x); ay += bf2f(v.y); az += bf2f(v.z); aw += bf2f(v.w);
            }
        }
    }
    if (act) {
        float dv = dis[node];
        ushort4 hv = hb4[(size_t)node * 24 + c];
        float4 bv = reinterpret_cast<const float4*>(b1)[c];
        ushort4 o;
        o.x = f2bf(fmaxf((ax + bf2f(hv.x)) * dv + bv.x, 0.f));
        o.y = f2bf(fmaxf((ay + bf2f(hv.y)) * dv + bv.y, 0.f));
        o.z = f2bf(fmaxf((az + bf2f(hv.z)) * dv + bv.z, 0.f));
        o.w = f2bf(fmaxf((aw + bf2f(hv.w)) * dv + bv.w, 0.f));
        hid4[(size_t)node * 24 + c] = o;
    }
}

// h23' = (hid @ W2) * dis[row], bf16 MFMA, LDS-free (W2T 12KB L1-hot)
#define GBM2 64
__global__ __launch_bounds__(256) void k_gemm2(const unsigned short* __restrict__ hid,
                                               const unsigned short* __restrict__ W2T,
                                               const float* __restrict__ dis,
                                               unsigned short* __restrict__ h23, int M) {
    int tid = threadIdx.x;
    int lane = tid & 63, w = tid >> 6;
    int l15 = lane & 15, hi = lane >> 4;
    int m0 = blockIdx.x * GBM2;
    int row = m0 + w * 16 + l15;
    const unsigned short* ap = hid + (size_t)min(row, M - 1) * NH + hi * 8;
    const unsigned short* bp = W2T + (size_t)l15 * NH + hi * 8;

    f32x4 acc[4];
#pragma unroll
    for (int nt = 0; nt < 4; ++nt)
#pragma unroll
        for (int i = 0; i < 4; ++i) acc[nt][i] = 0.f;

#pragma unroll
    for (int kc = 0; kc < 3; ++kc) {
        short8v av = *reinterpret_cast<const short8v*>(ap + kc * 32);
#pragma unroll
        for (int nt = 0; nt < 4; ++nt) {
            short8v bv = *reinterpret_cast<const short8v*>(bp + nt * 16 * NH + kc * 32);
            acc[nt] = __builtin_amdgcn_mfma_f32_16x16x32_bf16(av, bv, acc[nt], 0, 0, 0);
        }
    }

    int rbase = m0 + w * 16 + hi * 4;
#pragma unroll
    for (int r = 0; r < 4; ++r) {
        int orow = rbase + r;
        if (orow < M) {
            float dv = dis[orow];
            unsigned short* op = h23 + (size_t)orow * NH2 + l15;
#pragma unroll
            for (int nt = 0; nt < 4; ++nt) op[nt * 16] = f2bf(acc[nt][r] * dv);
        }
    }
}

// gather layer 2 (bf16 rows, 128B): out = (sum h23'[s] + h23'[i]) * dis + bias
__global__ __launch_bounds__(256) void k_gather2(const ushort4* __restrict__ hb4,
                                                 const int* __restrict__ rowoff,
                                                 const int* __restrict__ esrc,
                                                 const float* __restrict__ dis,
                                                 const float* __restrict__ bmu,
                                                 const float* __restrict__ bls,
                                                 float4* __restrict__ out4) {
    int tid = threadIdx.x;
    int node = blockIdx.x * 16 + (tid >> 4);
    int c = tid & 15;
    if (node >= N_NODES) return;
    int p0 = rowoff[node], p1 = rowoff[node + 1];
    float ax = 0.f, ay = 0.f, az = 0.f, aw = 0.f;
    for (int pb = p0; pb < p1; pb += 16) {
        int nb = min(16, p1 - pb);
        int sv = (c < nb) ? esrc[pb + c] : 0;
#pragma unroll 4
        for (int j = 0; j < nb; j++) {
            int s = __shfl(sv, j, 16);
            ushort4 v = hb4[(size_t)s * 16 + c];
            ax += bf2f(v.x); ay += bf2f(v.y); az += bf2f(v.z); aw += bf2f(v.w);
        }
    }
    float dv = dis[node];
    ushort4 hv = hb4[(size_t)node * 16 + c];
    float4 bv = (c < 8) ? reinterpret_cast<const float4*>(bmu)[c]
                        : reinterpret_cast<const float4*>(bls)[c - 8];
    float4 o;
    o.x = (ax + bf2f(hv.x)) * dv + bv.x;
    o.y = (ay + bf2f(hv.y)) * dv + bv.y;
    o.z = (az + bf2f(hv.z)) * dv + bv.z;
    o.w = (aw + bf2f(hv.w)) * dv + bv.w;
    if (c < 8) out4[(size_t)node * 8 + c] = o;
    else       out4[(size_t)N_NODES * 8 + (size_t)node * 8 + (c - 8)] = o;
}

extern "C" void kernel_launch(void* const* d_in, const int* in_sizes, int n_in,
                              void* d_out, int out_size, void* d_ws, size_t ws_size,
                              hipStream_t stream) {
    const float* x   = (const float*)d_in[0];
    const float* W1  = (const float*)d_in[1];
    const float* b1  = (const float*)d_in[2];
    const float* Wmu = (const float*)d_in[3];
    const float* bmu = (const float*)d_in[4];
    const float* Wls = (const float*)d_in[5];
    const float* bls = (const float*)d_in[6];
    const int*   ei  = (const int*)d_in[7];
    int E = in_sizes[7] / 2;
    const int* src  = ei;
    const int* dstp = ei + E;

    char* w = (char*)d_ws;
    int* degi    = (int*)w;            w += (size_t)N_NODES * 4;
    int* cur     = (int*)w;            w += (size_t)N_NODES * 4;
    int* rowoff  = (int*)w;            w += ((size_t)N_NODES + 4) * 4;
    float* dis   = (float*)w;          w += (size_t)N_NODES * 4;
    int* bsum    = (int*)w;            w += 64 * 4;
    int* boff    = (int*)w;            w += 64 * 4;
    int* esrc    = (int*)w;            w += (size_t)E * 4;
    unsigned short* WbT  = (unsigned short*)w;  w += (size_t)NH * NIN * 2;
    unsigned short* W2T  = (unsigned short*)w;  w += (size_t)NH2 * NH * 2;
    unsigned short* hbuf = (unsigned short*)w;  w += (size_t)N_NODES * NH * 2;
    unsigned short* hid  = (unsigned short*)w;  w += (size_t)N_NODES * NH * 2;
    unsigned short* h23  = (unsigned short*)w;  w += (size_t)N_NODES * NH2 * 2;

    int prep_n = NH * NIN + NH2 * NH;
    k_prep<<<(prep_n + 255) / 256, 256, 0, stream>>>(W1, Wmu, Wls, WbT, W2T, degi);

    k_degi<<<(E + 255) / 256, 256, 0, stream>>>(dstp, degi, E);
    k_scan1<<<SCAN_BLK, 256, 0, stream>>>(degi, bsum);
    k_scan2<<<1, 64, 0, stream>>>(bsum, boff);
    k_scan3<<<SCAN_BLK, 256, 0, stream>>>(degi, boff, rowoff, cur, dis);
    k_bucket<<<(E + 255) / 256, 256, 0, stream>>>(src, dstp, rowoff, cur, esrc, E);

    k_gemm1<<<(N_NODES + GBM - 1) / GBM, 256, 0, stream>>>(x, WbT, dis, hbuf, N_NODES);

    k_gather1<<<(N_NODES + 7) / 8, 256, 0, stream>>>(
        (const ushort4*)hbuf, rowoff, esrc, dis, b1, (ushort4*)hid);

    k_gemm2<<<(N_NODES + GBM2 - 1) / GBM2, 256, 0, stream>>>(hid, W2T, dis, h23, N_NODES);

    k_gather2<<<(N_NODES + 15) / 16, 256, 0, stream>>>(
        (const ushort4*)h23, rowoff, esrc, dis, bmu, bls, (float4*)d_out);
}